// Round 4
// baseline (1031.174 us; speedup 1.0000x reference)
//
#include <hip/hip_runtime.h>
#include <cstdint>
#include <cstddef>

#define D_DIM 2048
#define D_HID 8192
#define N_TOK 8192

typedef int v4i __attribute__((ext_vector_type(4)));

__device__ __forceinline__ void gload16(const void* g, void* l) {
  __builtin_amdgcn_global_load_lds(
      (__attribute__((address_space(1))) void*)(void*)(const_cast<void*>(g)),
      (__attribute__((address_space(3))) void*)(void*)(l), 16, 0, 0);
}

__device__ __forceinline__ unsigned pack4i8(int a, int b, int c, int d) {
  return (unsigned)(a & 255) | ((unsigned)(b & 255) << 8) |
         ((unsigned)(c & 255) << 16) | ((unsigned)(d & 255) << 24);
}

__device__ __forceinline__ int clampi(int v, int lo, int hi) {
  return v < lo ? lo : (v > hi ? hi : v);
}

// Branch-free exact-GELU via Abramowitz-Stegun 7.1.26 erf (|eps| <= 1.5e-7 abs).
__device__ __forceinline__ float gelu_fast(float c) {
  const float ax = fabsf(c) * 0.70710678118654752440f;  // |c|/sqrt(2)
  const float t = 1.0f / fmaf(0.3275911f, ax, 1.0f);
  const float poly =
      t * fmaf(t, fmaf(t, fmaf(t, fmaf(t, 1.061405429f, -1.453152027f),
                               1.421413741f), -0.284496736f), 0.254829592f);
  const float e = 1.0f - poly * __expf(-ax * ax);  // erf(|c|/sqrt2), >= 0
  const float es = copysignf(e, c);
  return 0.5f * c * (1.0f + es);
}

// ---------------- weight |w| sum (fixed-order f64, deterministic) ------------
__global__ __launch_bounds__(256) void wsum_k(const float* __restrict__ w1,
                                              const float* __restrict__ w2,
                                              double* __restrict__ part) {
  const int b = blockIdx.x;
  const float* w = (b < 1024) ? w1 : w2;
  const size_t base = (size_t)(b & 1023) * 16384;
  const int t = threadIdx.x;
  double s = 0.0;
  for (int i = 0; i < 64; ++i) s += fabs((double)w[base + (size_t)i * 256 + t]);
  __shared__ double red[256];
  red[t] = s;
  __syncthreads();
  for (int st = 128; st; st >>= 1) {
    if (t < st) red[t] += red[t + st];
    __syncthreads();
  }
  if (!t) part[b] = red[0];
}

__global__ __launch_bounds__(256) void wfinal_k(const double* __restrict__ part,
                                                double* __restrict__ swd,
                                                float* __restrict__ wsc) {
  __shared__ double red[256];
  const int t = threadIdx.x;
  for (int m = 0; m < 2; ++m) {
    double s = part[m * 1024 + t] + part[m * 1024 + 256 + t] +
               part[m * 1024 + 512 + t] + part[m * 1024 + 768 + t];
    red[t] = s;
    __syncthreads();
    for (int st = 128; st; st >>= 1) {
      if (t < st) red[t] += red[t + st];
      __syncthreads();
    }
    if (!t) {
      double mean = red[0] / 16777216.0;
      double m2 = fmax(mean, 1e-5);
      swd[m] = 1.0 / m2;
      wsc[m] = (float)m2;
    }
    __syncthreads();
  }
}

// ---------------- ternary weight quant (f64 decision, half-even) -------------
__global__ __launch_bounds__(256) void wquant_k(const float* __restrict__ w,
                                                int8_t* __restrict__ q,
                                                const double* __restrict__ swd, int idx) {
  const double s = swd[idx];
  const size_t i = ((size_t)blockIdx.x * 256 + threadIdx.x) * 4;
  const float4 v = *(const float4*)&w[i];
  const int q0 = clampi((int)__builtin_rint((double)v.x * s), -1, 1);
  const int q1 = clampi((int)__builtin_rint((double)v.y * s), -1, 1);
  const int q2 = clampi((int)__builtin_rint((double)v.z * s), -1, 1);
  const int q3 = clampi((int)__builtin_rint((double)v.w * s), -1, 1);
  *(unsigned*)&q[i] = pack4i8(q0, q1, q2, q3);
}

// ---------------- fused RMSNorm + per-token absmax int8 quant ----------------
__global__ __launch_bounds__(256) void rmsq_k(const float* __restrict__ x,
                                              const float* __restrict__ gamma,
                                              int8_t* __restrict__ qx,
                                              float* __restrict__ sxinv) {
  const int row = blockIdx.x, t = threadIdx.x;
  const float* xr = x + (size_t)row * D_DIM;
  const float4 v0 = *(const float4*)&xr[t * 4];
  const float4 v1 = *(const float4*)&xr[1024 + t * 4];
  double xs[8] = {v0.x, v0.y, v0.z, v0.w, v1.x, v1.y, v1.z, v1.w};
  double ssq = 0.0;
#pragma unroll
  for (int j = 0; j < 8; ++j) ssq += xs[j] * xs[j];
  __shared__ double red[256];
  red[t] = ssq;
  __syncthreads();
  for (int st = 128; st; st >>= 1) {
    if (t < st) red[t] += red[t + st];
    __syncthreads();
  }
  const double rn = 1.0 / sqrt(red[0] / (double)D_DIM + 1e-6);
  __syncthreads();
  const float4 g0 = *(const float4*)&gamma[t * 4];
  const float4 g1 = *(const float4*)&gamma[1024 + t * 4];
  const double gs[8] = {g0.x, g0.y, g0.z, g0.w, g1.x, g1.y, g1.z, g1.w};
  double xn[8], am = 0.0;
#pragma unroll
  for (int j = 0; j < 8; ++j) {
    xn[j] = xs[j] * rn * gs[j];
    am = fmax(am, fabs(xn[j]));
  }
  red[t] = am;
  __syncthreads();
  for (int st = 128; st; st >>= 1) {
    if (t < st) red[t] = fmax(red[t], red[t + st]);
    __syncthreads();
  }
  const double amax = fmax(red[0], 1e-5);
  const double s = 127.0 / amax;
  int q[8];
#pragma unroll
  for (int j = 0; j < 8; ++j) q[j] = clampi((int)__builtin_rint(xn[j] * s), -128, 127);
  unsigned* qo = (unsigned*)(qx + (size_t)row * D_DIM);
  qo[t] = pack4i8(q[0], q[1], q[2], q[3]);
  qo[256 + t] = pack4i8(q[4], q[5], q[6], q[7]);
  if (!t) sxinv[row] = (float)(amax / 127.0);
}

// ---------------- per-token quant of gelu(h) (path A only) -------------------
__global__ __launch_bounds__(256) void hquant_k(const float* __restrict__ g,
                                                int8_t* __restrict__ qh,
                                                const unsigned* __restrict__ amaxh,
                                                float* __restrict__ shinv) {
  const int row = blockIdx.x, t = threadIdx.x;
  const float* gr = g + (size_t)row * D_HID;
  const double am = fmax((double)__uint_as_float(amaxh[row]), 1e-5);
  const double s = 127.0 / am;
  if (!t) shinv[row] = (float)(am / 127.0);
  unsigned* qo = (unsigned*)(qh + (size_t)row * D_HID);
#pragma unroll
  for (int j = 0; j < 8; ++j) {
    const float4 v = *(const float4*)&gr[j * 1024 + t * 4];
    const int q0 = clampi((int)__builtin_rint((double)v.x * s), -128, 127);
    const int q1 = clampi((int)__builtin_rint((double)v.y * s), -128, 127);
    const int q2 = clampi((int)__builtin_rint((double)v.z * s), -128, 127);
    const int q3 = clampi((int)__builtin_rint((double)v.w * s), -128, 127);
    qo[j * 256 + t] = pack4i8(q0, q1, q2, q3);
  }
}

__global__ __launch_bounds__(256) void scalefix_k(const unsigned* __restrict__ amaxh,
                                                  float* __restrict__ shinv) {
  const int i = blockIdx.x * 256 + threadIdx.x;
  if (i < N_TOK)
    shinv[i] = (float)(fmax((double)__uint_as_float(amaxh[i]), 1e-5) / 127.0);
}

// ---------------- int8 NT GEMM, 128x128 tile, BK=64 --------------------------
// A [M,K] int8 row-major, B [N,K] int8 row-major (NT).
// LDS: 8 subblocks of 1024B per operand; subblock mb = [4 kslots][16 rows][16B].
// Staging lane l fetches row (l&15), kchunk (l>>4) -> linear LDS slot l.
// Fragment read offset hi*256 + lo*16: 16-lane groups read 256B contiguous ->
// 2-way bank aliasing only (free). (Conflict-free layout validated in R3 run.)
// EPI=0: gelu rowmax only; 1: gelu + f32 store + rowmax; 2: dequant store;
// 3: gelu + int8 quant store.
template <int EPI>
__global__ __launch_bounds__(256) void gemm_i8_k(const int8_t* __restrict__ A,
                                                 const int8_t* __restrict__ B, int K,
                                                 float* __restrict__ Cf,
                                                 int8_t* __restrict__ Cq, int ldc,
                                                 const float* __restrict__ rowf,
                                                 const float* __restrict__ wscp,
                                                 unsigned* __restrict__ amax) {
  __shared__ __align__(16) int8_t Al[128 * 64];
  __shared__ __align__(16) int8_t Bl[128 * 64];
  const int tid = threadIdx.x;
  const int wave = tid >> 6, lane = tid & 63;
  const int hi = lane >> 4, lo = lane & 15;
  const int row0 = blockIdx.y * 128, col0 = blockIdx.x * 128;
  const int wr = (wave >> 1) * 64, wc = (wave & 1) * 64;

  v4i acc[4][4];
#pragma unroll
  for (int m = 0; m < 4; ++m)
#pragma unroll
    for (int n = 0; n < 4; ++n) acc[m][n] = (v4i){0, 0, 0, 0};

  // staging source permutation matching [kslot][row16][16B] subblocks
  const int srow = lane & 15;
  const int skb = (lane >> 4) * 16;

  for (int k0 = 0; k0 < K; k0 += 64) {
#pragma unroll
    for (int i = 0; i < 2; ++i) {
      const int mb = i * 4 + wave;
      gload16(A + (size_t)(row0 + mb * 16 + srow) * K + k0 + skb, &Al[mb * 1024]);
      gload16(B + (size_t)(col0 + mb * 16 + srow) * K + k0 + skb, &Bl[mb * 1024]);
    }
    __syncthreads();
    v4i af[4], bf[4];
    const int roff = hi * 256 + lo * 16;  // row lo, kslot hi within subblock
#pragma unroll
    for (int m = 0; m < 4; ++m) af[m] = *(const v4i*)&Al[((wr >> 4) + m) * 1024 + roff];
#pragma unroll
    for (int n = 0; n < 4; ++n) bf[n] = *(const v4i*)&Bl[((wc >> 4) + n) * 1024 + roff];
#pragma unroll
    for (int m = 0; m < 4; ++m)
#pragma unroll
      for (int n = 0; n < 4; ++n)
        acc[m][n] = __builtin_amdgcn_mfma_i32_16x16x64_i8(af[m], bf[n], acc[m][n], 0, 0, 0);
    __syncthreads();
  }

  const float mw = wscp[0];
#pragma unroll
  for (int m = 0; m < 4; ++m) {
#pragma unroll
    for (int r = 0; r < 4; ++r) {
      const int grow = row0 + wr + m * 16 + hi * 4 + r;
      const float f = rowf[grow] * mw;
      if constexpr (EPI == 0 || EPI == 1) {
        float rmax = 0.f;
#pragma unroll
        for (int n = 0; n < 4; ++n) {
          const int gcol = col0 + wc + n * 16 + lo;
          const float c = (float)acc[m][n][r] * f;
          const float gv = gelu_fast(c);
          if constexpr (EPI == 1) Cf[(size_t)grow * ldc + gcol] = gv;
          rmax = fmaxf(rmax, fabsf(gv));
        }
#pragma unroll
        for (int sh = 1; sh < 16; sh <<= 1) rmax = fmaxf(rmax, __shfl_xor(rmax, sh));
        if (lo == 0) atomicMax(&amax[grow], __float_as_uint(rmax));
      } else if constexpr (EPI == 3) {
        const double s = 127.0 / fmax((double)__uint_as_float(amax[grow]), 1e-5);
#pragma unroll
        for (int n = 0; n < 4; ++n) {
          const int gcol = col0 + wc + n * 16 + lo;
          const float c = (float)acc[m][n][r] * f;
          const float gv = gelu_fast(c);
          Cq[(size_t)grow * ldc + gcol] =
              (int8_t)clampi((int)__builtin_rint((double)gv * s), -128, 127);
        }
      } else {
#pragma unroll
        for (int n = 0; n < 4; ++n) {
          const int gcol = col0 + wc + n * 16 + lo;
          Cf[(size_t)grow * ldc + gcol] = (float)acc[m][n][r] * f;
        }
      }
    }
  }
}

__global__ void fill_k(float* p, int n, float v) {
  int i = blockIdx.x * 256 + threadIdx.x;
  if (i < n) p[i] = v;
}

extern "C" void kernel_launch(void* const* d_in, const int* in_sizes, int n_in, void* d_out,
                              int out_size, void* d_ws, size_t ws_size, hipStream_t stream) {
  const float* x = (const float*)d_in[0];
  const float* w1 = (const float*)d_in[1];
  const float* w2 = (const float*)d_in[2];
  const float* gamma = (const float*)d_in[3];
  float* out = (float*)d_out;
  char* ws = (char*)d_ws;

  const size_t SQX = (size_t)N_TOK * D_DIM;
  const size_t SQW1 = (size_t)D_HID * D_DIM;
  const size_t SQW2 = (size_t)D_DIM * D_HID;
  const size_t SQH = (size_t)N_TOK * D_HID;
  const size_t SG = (size_t)N_TOK * D_HID * 4;

  size_t off = 0;
  int8_t* qx = (int8_t*)(ws + off);  off += SQX;
  int8_t* qw1 = (int8_t*)(ws + off); off += SQW1;
  int8_t* qw2 = (int8_t*)(ws + off); off += SQW2;
  int8_t* qh = (int8_t*)(ws + off);  off += SQH;
  float* sxinv = (float*)(ws + off);       off += (size_t)N_TOK * 4;
  unsigned* amaxh = (unsigned*)(ws + off); off += (size_t)N_TOK * 4;
  float* shinv = (float*)(ws + off);       off += (size_t)N_TOK * 4;
  double* wpart = (double*)(ws + off);     off += 2048 * 8;
  double* swd = (double*)(ws + off);       off += 2 * 8;
  float* wsc = (float*)(ws + off);         off += 2 * 4;
  const size_t needB = off;
  float* g = (float*)(ws + off);
  const size_t needA = off + SG;

  if (ws_size < needB) {
    const float v = 100000.0f + (float)(ws_size >> 20);
    fill_k<<<(out_size + 255) / 256, 256, 0, stream>>>(out, out_size, v);
    return;
  }
  const bool pathA = (ws_size >= needA);

  hipMemsetAsync(amaxh, 0, (size_t)N_TOK * 4, stream);
  wsum_k<<<2048, 256, 0, stream>>>(w1, w2, wpart);
  wfinal_k<<<1, 256, 0, stream>>>(wpart, swd, wsc);
  wquant_k<<<16384, 256, 0, stream>>>(w1, qw1, swd, 0);
  wquant_k<<<16384, 256, 0, stream>>>(w2, qw2, swd, 1);
  rmsq_k<<<N_TOK, 256, 0, stream>>>(x, gamma, qx, sxinv);

  const dim3 grid1(D_HID / 128, N_TOK / 128);
  const dim3 grid2(D_DIM / 128, N_TOK / 128);
  if (pathA) {
    gemm_i8_k<1><<<grid1, 256, 0, stream>>>(qx, qw1, D_DIM, g, nullptr, D_HID,
                                            sxinv, wsc + 0, amaxh);
    hquant_k<<<N_TOK, 256, 0, stream>>>(g, qh, amaxh, shinv);
  } else {
    gemm_i8_k<0><<<grid1, 256, 0, stream>>>(qx, qw1, D_DIM, nullptr, nullptr, D_HID,
                                            sxinv, wsc + 0, amaxh);
    scalefix_k<<<(N_TOK + 255) / 256, 256, 0, stream>>>(amaxh, shinv);
    gemm_i8_k<3><<<grid1, 256, 0, stream>>>(qx, qw1, D_DIM, nullptr, qh, D_HID,
                                            sxinv, wsc + 0, amaxh);
  }
  gemm_i8_k<2><<<grid2, 256, 0, stream>>>(qh, qw2, D_HID, out, nullptr, D_DIM,
                                          shinv, wsc + 1, nullptr);
}

// Round 5
// 772.071 us; speedup vs baseline: 1.3356x; 1.3356x over previous
//
#include <hip/hip_runtime.h>
#include <cstdint>
#include <cstddef>

#define D_DIM 2048
#define D_HID 8192
#define N_TOK 8192

typedef int v4i __attribute__((ext_vector_type(4)));

__device__ __forceinline__ void gload16(const void* g, void* l) {
  __builtin_amdgcn_global_load_lds(
      (__attribute__((address_space(1))) void*)(void*)(const_cast<void*>(g)),
      (__attribute__((address_space(3))) void*)(void*)(l), 16, 0, 0);
}

__device__ __forceinline__ unsigned pack4i8(int a, int b, int c, int d) {
  return (unsigned)(a & 255) | ((unsigned)(b & 255) << 8) |
         ((unsigned)(c & 255) << 16) | ((unsigned)(d & 255) << 24);
}

__device__ __forceinline__ int clampi(int v, int lo, int hi) {
  return v < lo ? lo : (v > hi ? hi : v);
}

// Branch-free exact-GELU via Abramowitz-Stegun 7.1.26 erf (|eps| <= 1.5e-7 abs).
__device__ __forceinline__ float gelu_fast(float c) {
  const float ax = fabsf(c) * 0.70710678118654752440f;  // |c|/sqrt(2)
  const float t = 1.0f / fmaf(0.3275911f, ax, 1.0f);
  const float poly =
      t * fmaf(t, fmaf(t, fmaf(t, fmaf(t, 1.061405429f, -1.453152027f),
                               1.421413741f), -0.284496736f), 0.254829592f);
  const float e = 1.0f - poly * __expf(-ax * ax);  // erf(|c|/sqrt2), >= 0
  const float es = copysignf(e, c);
  return 0.5f * c * (1.0f + es);
}

// ---------------- weight |w| sum (fixed-order f64, deterministic) ------------
__global__ __launch_bounds__(256) void wsum_k(const float* __restrict__ w1,
                                              const float* __restrict__ w2,
                                              double* __restrict__ part) {
  const int b = blockIdx.x;
  const float* w = (b < 1024) ? w1 : w2;
  const size_t base = (size_t)(b & 1023) * 16384;
  const int t = threadIdx.x;
  double s = 0.0;
  for (int i = 0; i < 64; ++i) s += fabs((double)w[base + (size_t)i * 256 + t]);
  __shared__ double red[256];
  red[t] = s;
  __syncthreads();
  for (int st = 128; st; st >>= 1) {
    if (t < st) red[t] += red[t + st];
    __syncthreads();
  }
  if (!t) part[b] = red[0];
}

__global__ __launch_bounds__(256) void wfinal_k(const double* __restrict__ part,
                                                double* __restrict__ swd,
                                                float* __restrict__ wsc) {
  __shared__ double red[256];
  const int t = threadIdx.x;
  for (int m = 0; m < 2; ++m) {
    double s = part[m * 1024 + t] + part[m * 1024 + 256 + t] +
               part[m * 1024 + 512 + t] + part[m * 1024 + 768 + t];
    red[t] = s;
    __syncthreads();
    for (int st = 128; st; st >>= 1) {
      if (t < st) red[t] += red[t + st];
      __syncthreads();
    }
    if (!t) {
      double mean = red[0] / 16777216.0;
      double m2 = fmax(mean, 1e-5);
      swd[m] = 1.0 / m2;
      wsc[m] = (float)m2;
    }
    __syncthreads();
  }
}

// ---------------- ternary weight quant (f64 decision, half-even) -------------
__global__ __launch_bounds__(256) void wquant_k(const float* __restrict__ w,
                                                int8_t* __restrict__ q,
                                                const double* __restrict__ swd, int idx) {
  const double s = swd[idx];
  const size_t i = ((size_t)blockIdx.x * 256 + threadIdx.x) * 4;
  const float4 v = *(const float4*)&w[i];
  const int q0 = clampi((int)__builtin_rint((double)v.x * s), -1, 1);
  const int q1 = clampi((int)__builtin_rint((double)v.y * s), -1, 1);
  const int q2 = clampi((int)__builtin_rint((double)v.z * s), -1, 1);
  const int q3 = clampi((int)__builtin_rint((double)v.w * s), -1, 1);
  *(unsigned*)&q[i] = pack4i8(q0, q1, q2, q3);
}

// ---------------- fused RMSNorm + per-token absmax int8 quant ----------------
__global__ __launch_bounds__(256) void rmsq_k(const float* __restrict__ x,
                                              const float* __restrict__ gamma,
                                              int8_t* __restrict__ qx,
                                              float* __restrict__ sxinv) {
  const int row = blockIdx.x, t = threadIdx.x;
  const float* xr = x + (size_t)row * D_DIM;
  const float4 v0 = *(const float4*)&xr[t * 4];
  const float4 v1 = *(const float4*)&xr[1024 + t * 4];
  double xs[8] = {v0.x, v0.y, v0.z, v0.w, v1.x, v1.y, v1.z, v1.w};
  double ssq = 0.0;
#pragma unroll
  for (int j = 0; j < 8; ++j) ssq += xs[j] * xs[j];
  __shared__ double red[256];
  red[t] = ssq;
  __syncthreads();
  for (int st = 128; st; st >>= 1) {
    if (t < st) red[t] += red[t + st];
    __syncthreads();
  }
  const double rn = 1.0 / sqrt(red[0] / (double)D_DIM + 1e-6);
  __syncthreads();
  const float4 g0 = *(const float4*)&gamma[t * 4];
  const float4 g1 = *(const float4*)&gamma[1024 + t * 4];
  const double gs[8] = {g0.x, g0.y, g0.z, g0.w, g1.x, g1.y, g1.z, g1.w};
  double xn[8], am = 0.0;
#pragma unroll
  for (int j = 0; j < 8; ++j) {
    xn[j] = xs[j] * rn * gs[j];
    am = fmax(am, fabs(xn[j]));
  }
  red[t] = am;
  __syncthreads();
  for (int st = 128; st; st >>= 1) {
    if (t < st) red[t] = fmax(red[t], red[t + st]);
    __syncthreads();
  }
  const double amax = fmax(red[0], 1e-5);
  const double s = 127.0 / amax;
  int q[8];
#pragma unroll
  for (int j = 0; j < 8; ++j) q[j] = clampi((int)__builtin_rint(xn[j] * s), -128, 127);
  unsigned* qo = (unsigned*)(qx + (size_t)row * D_DIM);
  qo[t] = pack4i8(q[0], q[1], q[2], q[3]);
  qo[256 + t] = pack4i8(q[4], q[5], q[6], q[7]);
  if (!t) sxinv[row] = (float)(amax / 127.0);
}

// ---------------- per-token quant of gelu(h) (path A only) -------------------
__global__ __launch_bounds__(256) void hquant_k(const float* __restrict__ g,
                                                int8_t* __restrict__ qh,
                                                const unsigned* __restrict__ amaxh,
                                                float* __restrict__ shinv) {
  const int row = blockIdx.x, t = threadIdx.x;
  const float* gr = g + (size_t)row * D_HID;
  const double am = fmax((double)__uint_as_float(amaxh[row]), 1e-5);
  const double s = 127.0 / am;
  if (!t) shinv[row] = (float)(am / 127.0);
  unsigned* qo = (unsigned*)(qh + (size_t)row * D_HID);
#pragma unroll
  for (int j = 0; j < 8; ++j) {
    const float4 v = *(const float4*)&gr[j * 1024 + t * 4];
    const int q0 = clampi((int)__builtin_rint((double)v.x * s), -128, 127);
    const int q1 = clampi((int)__builtin_rint((double)v.y * s), -128, 127);
    const int q2 = clampi((int)__builtin_rint((double)v.z * s), -128, 127);
    const int q3 = clampi((int)__builtin_rint((double)v.w * s), -128, 127);
    qo[j * 256 + t] = pack4i8(q0, q1, q2, q3);
  }
}

__global__ __launch_bounds__(256) void scalefix_k(const unsigned* __restrict__ amaxh,
                                                  float* __restrict__ shinv) {
  const int i = blockIdx.x * 256 + threadIdx.x;
  if (i < N_TOK)
    shinv[i] = (float)(fmax((double)__uint_as_float(amaxh[i]), 1e-5) / 127.0);
}

// ---------------- int8 NT GEMM, 128x128 tile, BK=64 --------------------------
// A [M,K] int8 row-major, B [N,K] int8 row-major (NT).
// LDS: 8 subblocks of 1024B per operand. Slot s (16B) of a subblock holds
//   row = s>>2, kchunk = (s&3) ^ ((s>>3)&3)   (XOR-permuted within each row).
// Staging (global_load_lds writes slot=lane): lanes 0-3 read row0's 64B
// (chunks permuted), lanes 4-7 row1, ... -> same 4x64B-contiguous quarter-wave
// coalescing as the fast R2 kernel.
// Fragment read (row=lo, kchunk=hi): roff = 64*lo + 16*(hi ^ ((lo>>1)&3));
// bank-quad = (4*lo + hi^((lo>>1)&3)) mod 8: lanes 0-7 hit 8 distinct quads,
// 16-lane group exactly 2-way (free) -> kills R2's 8-way conflict.
// EPI=0: gelu rowmax only; 1: gelu + f32 store + rowmax; 2: dequant store;
// 3: gelu + int8 quant store.
template <int EPI>
__global__ __launch_bounds__(256) void gemm_i8_k(const int8_t* __restrict__ A,
                                                 const int8_t* __restrict__ B, int K,
                                                 float* __restrict__ Cf,
                                                 int8_t* __restrict__ Cq, int ldc,
                                                 const float* __restrict__ rowf,
                                                 const float* __restrict__ wscp,
                                                 unsigned* __restrict__ amax) {
  __shared__ __align__(16) int8_t Al[128 * 64];
  __shared__ __align__(16) int8_t Bl[128 * 64];
  const int tid = threadIdx.x;
  const int wave = tid >> 6, lane = tid & 63;
  const int hi = lane >> 4, lo = lane & 15;
  const int row0 = blockIdx.y * 128, col0 = blockIdx.x * 128;
  const int wr = (wave >> 1) * 64, wc = (wave & 1) * 64;

  v4i acc[4][4];
#pragma unroll
  for (int m = 0; m < 4; ++m)
#pragma unroll
    for (int n = 0; n < 4; ++n) acc[m][n] = (v4i){0, 0, 0, 0};

  // staging source: row (lane>>2), kchunk (lane&3)^((lane>>3)&3)
  const int srow = lane >> 2;
  const int skb = ((lane & 3) ^ ((lane >> 3) & 3)) * 16;

  for (int k0 = 0; k0 < K; k0 += 64) {
#pragma unroll
    for (int i = 0; i < 2; ++i) {
      const int mb = i * 4 + wave;
      gload16(A + (size_t)(row0 + mb * 16 + srow) * K + k0 + skb, &Al[mb * 1024]);
      gload16(B + (size_t)(col0 + mb * 16 + srow) * K + k0 + skb, &Bl[mb * 1024]);
    }
    __syncthreads();
    v4i af[4], bf[4];
    const int roff = lo * 64 + ((hi ^ ((lo >> 1) & 3)) * 16);
#pragma unroll
    for (int m = 0; m < 4; ++m) af[m] = *(const v4i*)&Al[((wr >> 4) + m) * 1024 + roff];
#pragma unroll
    for (int n = 0; n < 4; ++n) bf[n] = *(const v4i*)&Bl[((wc >> 4) + n) * 1024 + roff];
#pragma unroll
    for (int m = 0; m < 4; ++m)
#pragma unroll
      for (int n = 0; n < 4; ++n)
        acc[m][n] = __builtin_amdgcn_mfma_i32_16x16x64_i8(af[m], bf[n], acc[m][n], 0, 0, 0);
    __syncthreads();
  }

  const float mw = wscp[0];
#pragma unroll
  for (int m = 0; m < 4; ++m) {
#pragma unroll
    for (int r = 0; r < 4; ++r) {
      const int grow = row0 + wr + m * 16 + hi * 4 + r;
      const float f = rowf[grow] * mw;
      if constexpr (EPI == 0 || EPI == 1) {
        float rmax = 0.f;
#pragma unroll
        for (int n = 0; n < 4; ++n) {
          const int gcol = col0 + wc + n * 16 + lo;
          const float c = (float)acc[m][n][r] * f;
          const float gv = gelu_fast(c);
          if constexpr (EPI == 1) Cf[(size_t)grow * ldc + gcol] = gv;
          rmax = fmaxf(rmax, fabsf(gv));
        }
#pragma unroll
        for (int sh = 1; sh < 16; sh <<= 1) rmax = fmaxf(rmax, __shfl_xor(rmax, sh));
        if (lo == 0) atomicMax(&amax[grow], __float_as_uint(rmax));
      } else if constexpr (EPI == 3) {
        const double s = 127.0 / fmax((double)__uint_as_float(amax[grow]), 1e-5);
#pragma unroll
        for (int n = 0; n < 4; ++n) {
          const int gcol = col0 + wc + n * 16 + lo;
          const float c = (float)acc[m][n][r] * f;
          const float gv = gelu_fast(c);
          Cq[(size_t)grow * ldc + gcol] =
              (int8_t)clampi((int)__builtin_rint((double)gv * s), -128, 127);
        }
      } else {
#pragma unroll
        for (int n = 0; n < 4; ++n) {
          const int gcol = col0 + wc + n * 16 + lo;
          Cf[(size_t)grow * ldc + gcol] = (float)acc[m][n][r] * f;
        }
      }
    }
  }
}

__global__ void fill_k(float* p, int n, float v) {
  int i = blockIdx.x * 256 + threadIdx.x;
  if (i < n) p[i] = v;
}

extern "C" void kernel_launch(void* const* d_in, const int* in_sizes, int n_in, void* d_out,
                              int out_size, void* d_ws, size_t ws_size, hipStream_t stream) {
  const float* x = (const float*)d_in[0];
  const float* w1 = (const float*)d_in[1];
  const float* w2 = (const float*)d_in[2];
  const float* gamma = (const float*)d_in[3];
  float* out = (float*)d_out;
  char* ws = (char*)d_ws;

  const size_t SQX = (size_t)N_TOK * D_DIM;
  const size_t SQW1 = (size_t)D_HID * D_DIM;
  const size_t SQW2 = (size_t)D_DIM * D_HID;
  const size_t SQH = (size_t)N_TOK * D_HID;
  const size_t SG = (size_t)N_TOK * D_HID * 4;

  size_t off = 0;
  int8_t* qx = (int8_t*)(ws + off);  off += SQX;
  int8_t* qw1 = (int8_t*)(ws + off); off += SQW1;
  int8_t* qw2 = (int8_t*)(ws + off); off += SQW2;
  int8_t* qh = (int8_t*)(ws + off);  off += SQH;
  float* sxinv = (float*)(ws + off);       off += (size_t)N_TOK * 4;
  unsigned* amaxh = (unsigned*)(ws + off); off += (size_t)N_TOK * 4;
  float* shinv = (float*)(ws + off);       off += (size_t)N_TOK * 4;
  double* wpart = (double*)(ws + off);     off += 2048 * 8;
  double* swd = (double*)(ws + off);       off += 2 * 8;
  float* wsc = (float*)(ws + off);         off += 2 * 4;
  const size_t needB = off;
  float* g = (float*)(ws + off);
  const size_t needA = off + SG;

  if (ws_size < needB) {
    const float v = 100000.0f + (float)(ws_size >> 20);
    fill_k<<<(out_size + 255) / 256, 256, 0, stream>>>(out, out_size, v);
    return;
  }
  const bool pathA = (ws_size >= needA);

  hipMemsetAsync(amaxh, 0, (size_t)N_TOK * 4, stream);
  wsum_k<<<2048, 256, 0, stream>>>(w1, w2, wpart);
  wfinal_k<<<1, 256, 0, stream>>>(wpart, swd, wsc);
  wquant_k<<<16384, 256, 0, stream>>>(w1, qw1, swd, 0);
  wquant_k<<<16384, 256, 0, stream>>>(w2, qw2, swd, 1);
  rmsq_k<<<N_TOK, 256, 0, stream>>>(x, gamma, qx, sxinv);

  const dim3 grid1(D_HID / 128, N_TOK / 128);
  const dim3 grid2(D_DIM / 128, N_TOK / 128);
  if (pathA) {
    gemm_i8_k<1><<<grid1, 256, 0, stream>>>(qx, qw1, D_DIM, g, nullptr, D_HID,
                                            sxinv, wsc + 0, amaxh);
    hquant_k<<<N_TOK, 256, 0, stream>>>(g, qh, amaxh, shinv);
  } else {
    gemm_i8_k<0><<<grid1, 256, 0, stream>>>(qx, qw1, D_DIM, nullptr, nullptr, D_HID,
                                            sxinv, wsc + 0, amaxh);
    scalefix_k<<<(N_TOK + 255) / 256, 256, 0, stream>>>(amaxh, shinv);
    gemm_i8_k<3><<<grid1, 256, 0, stream>>>(qx, qw1, D_DIM, nullptr, qh, D_HID,
                                            sxinv, wsc + 0, amaxh);
  }
  gemm_i8_k<2><<<grid2, 256, 0, stream>>>(qh, qw2, D_HID, out, nullptr, D_DIM,
                                          shinv, wsc + 1, nullptr);
}

// Round 6
// 614.815 us; speedup vs baseline: 1.6772x; 1.2558x over previous
//
#include <hip/hip_runtime.h>
#include <cstdint>
#include <cstddef>

#define D_DIM 2048
#define D_HID 8192
#define N_TOK 8192

typedef int v4i __attribute__((ext_vector_type(4)));

__device__ __forceinline__ void gload16(const void* g, void* l) {
  __builtin_amdgcn_global_load_lds(
      (__attribute__((address_space(1))) void*)(void*)(const_cast<void*>(g)),
      (__attribute__((address_space(3))) void*)(void*)(l), 16, 0, 0);
}

__device__ __forceinline__ unsigned pack4i8(int a, int b, int c, int d) {
  return (unsigned)(a & 255) | ((unsigned)(b & 255) << 8) |
         ((unsigned)(c & 255) << 16) | ((unsigned)(d & 255) << 24);
}

__device__ __forceinline__ int clampi(int v, int lo, int hi) {
  return v < lo ? lo : (v > hi ? hi : v);
}

// Branch-free exact-GELU via Abramowitz-Stegun 7.1.26 erf (|eps| <= 1.5e-7 abs).
__device__ __forceinline__ float gelu_fast(float c) {
  const float ax = fabsf(c) * 0.70710678118654752440f;
  const float t = 1.0f / fmaf(0.3275911f, ax, 1.0f);
  const float poly =
      t * fmaf(t, fmaf(t, fmaf(t, fmaf(t, 1.061405429f, -1.453152027f),
                               1.421413741f), -0.284496736f), 0.254829592f);
  const float e = 1.0f - poly * __expf(-ax * ax);
  const float es = copysignf(e, c);
  return 0.5f * c * (1.0f + es);
}

// ---------------- weight |w| sum (fixed-order f64, deterministic) ------------
__global__ __launch_bounds__(256) void wsum_k(const float* __restrict__ w1,
                                              const float* __restrict__ w2,
                                              double* __restrict__ part) {
  const int b = blockIdx.x;
  const float* w = (b < 1024) ? w1 : w2;
  const size_t base = (size_t)(b & 1023) * 16384;
  const int t = threadIdx.x;
  double s = 0.0;
  for (int i = 0; i < 64; ++i) s += fabs((double)w[base + (size_t)i * 256 + t]);
  __shared__ double red[256];
  red[t] = s;
  __syncthreads();
  for (int st = 128; st; st >>= 1) {
    if (t < st) red[t] += red[t + st];
    __syncthreads();
  }
  if (!t) part[b] = red[0];
}

__global__ __launch_bounds__(256) void wfinal_k(const double* __restrict__ part,
                                                double* __restrict__ swd,
                                                float* __restrict__ wsc) {
  __shared__ double red[256];
  const int t = threadIdx.x;
  for (int m = 0; m < 2; ++m) {
    double s = part[m * 1024 + t] + part[m * 1024 + 256 + t] +
               part[m * 1024 + 512 + t] + part[m * 1024 + 768 + t];
    red[t] = s;
    __syncthreads();
    for (int st = 128; st; st >>= 1) {
      if (t < st) red[t] += red[t + st];
      __syncthreads();
    }
    if (!t) {
      double mean = red[0] / 16777216.0;
      double m2 = fmax(mean, 1e-5);
      swd[m] = 1.0 / m2;
      wsc[m] = (float)m2;
    }
    __syncthreads();
  }
}

// ---------------- ternary weight quant (f64 decision, half-even) -------------
__global__ __launch_bounds__(256) void wquant_k(const float* __restrict__ w,
                                                int8_t* __restrict__ q,
                                                const double* __restrict__ swd, int idx) {
  const double s = swd[idx];
  const size_t i = ((size_t)blockIdx.x * 256 + threadIdx.x) * 4;
  const float4 v = *(const float4*)&w[i];
  const int q0 = clampi((int)__builtin_rint((double)v.x * s), -1, 1);
  const int q1 = clampi((int)__builtin_rint((double)v.y * s), -1, 1);
  const int q2 = clampi((int)__builtin_rint((double)v.z * s), -1, 1);
  const int q3 = clampi((int)__builtin_rint((double)v.w * s), -1, 1);
  *(unsigned*)&q[i] = pack4i8(q0, q1, q2, q3);
}

// ---------------- fused RMSNorm + per-token absmax int8 quant ----------------
__global__ __launch_bounds__(256) void rmsq_k(const float* __restrict__ x,
                                              const float* __restrict__ gamma,
                                              int8_t* __restrict__ qx,
                                              float* __restrict__ sxinv) {
  const int row = blockIdx.x, t = threadIdx.x;
  const float* xr = x + (size_t)row * D_DIM;
  const float4 v0 = *(const float4*)&xr[t * 4];
  const float4 v1 = *(const float4*)&xr[1024 + t * 4];
  double xs[8] = {v0.x, v0.y, v0.z, v0.w, v1.x, v1.y, v1.z, v1.w};
  double ssq = 0.0;
#pragma unroll
  for (int j = 0; j < 8; ++j) ssq += xs[j] * xs[j];
  __shared__ double red[256];
  red[t] = ssq;
  __syncthreads();
  for (int st = 128; st; st >>= 1) {
    if (t < st) red[t] += red[t + st];
    __syncthreads();
  }
  const double rn = 1.0 / sqrt(red[0] / (double)D_DIM + 1e-6);
  __syncthreads();
  const float4 g0 = *(const float4*)&gamma[t * 4];
  const float4 g1 = *(const float4*)&gamma[1024 + t * 4];
  const double gs[8] = {g0.x, g0.y, g0.z, g0.w, g1.x, g1.y, g1.z, g1.w};
  double xn[8], am = 0.0;
#pragma unroll
  for (int j = 0; j < 8; ++j) {
    xn[j] = xs[j] * rn * gs[j];
    am = fmax(am, fabs(xn[j]));
  }
  red[t] = am;
  __syncthreads();
  for (int st = 128; st; st >>= 1) {
    if (t < st) red[t] = fmax(red[t], red[t + st]);
    __syncthreads();
  }
  const double amax = fmax(red[0], 1e-5);
  const double s = 127.0 / amax;
  int q[8];
#pragma unroll
  for (int j = 0; j < 8; ++j) q[j] = clampi((int)__builtin_rint(xn[j] * s), -128, 127);
  unsigned* qo = (unsigned*)(qx + (size_t)row * D_DIM);
  qo[t] = pack4i8(q[0], q[1], q[2], q[3]);
  qo[256 + t] = pack4i8(q[4], q[5], q[6], q[7]);
  if (!t) sxinv[row] = (float)(amax / 127.0);
}

// ---------------- per-token quant of gelu(h) (path A only) -------------------
__global__ __launch_bounds__(256) void hquant_k(const float* __restrict__ g,
                                                int8_t* __restrict__ qh,
                                                const unsigned* __restrict__ amaxh,
                                                float* __restrict__ shinv) {
  const int row = blockIdx.x, t = threadIdx.x;
  const float* gr = g + (size_t)row * D_HID;
  const double am = fmax((double)__uint_as_float(amaxh[row]), 1e-5);
  const double s = 127.0 / am;
  if (!t) shinv[row] = (float)(am / 127.0);
  unsigned* qo = (unsigned*)(qh + (size_t)row * D_HID);
#pragma unroll
  for (int j = 0; j < 8; ++j) {
    const float4 v = *(const float4*)&gr[j * 1024 + t * 4];
    const int q0 = clampi((int)__builtin_rint((double)v.x * s), -128, 127);
    const int q1 = clampi((int)__builtin_rint((double)v.y * s), -128, 127);
    const int q2 = clampi((int)__builtin_rint((double)v.z * s), -128, 127);
    const int q3 = clampi((int)__builtin_rint((double)v.w * s), -128, 127);
    qo[j * 256 + t] = pack4i8(q0, q1, q2, q3);
  }
}

__global__ __launch_bounds__(256) void scalefix_k(const unsigned* __restrict__ amaxh,
                                                  float* __restrict__ shinv) {
  const int i = blockIdx.x * 256 + threadIdx.x;
  if (i < N_TOK)
    shinv[i] = (float)(fmax((double)__uint_as_float(amaxh[i]), 1e-5) / 127.0);
}

// ======== int8 NT GEMM, 256x256 tile, BK=128 (2 K-halves), 8-phase ==========
// 8 waves (2M x 4N), per-wave 128x64 = acc[8][4]. LDS 128 KiB: regions
// {A,B} x {buf0,1} x {half0,1}, each 16 KiB = 16 subblocks of 1024B.
// Subblock slot s: row s>>2, kchunk (s&3)^((s>>3)&3)  (conflict-free reads,
// coalesced 4rows-x-64B staging; validated R5: SQ_LDS_BANK_CONFLICT = 0).
// Schedule (derived from region lifetimes; queue never drains):
//   P1 ds(b0h0 m0-3,b0-3) stg A[1][1](T+1) | P2 ds(m4-7) stg B[1][1](T+1) vm8
//   P3 ds(b0h1 ...)       stg A[0][0](T+2) | P4 ...      stg B[0][0](T+2) vm8
//   P5 ds(b1h0 ...)       stg A[0][1](T+2) | P6 ...      stg B[0][1](T+2) vm8
//   P7 ds(b1h1 ...)       stg A[1][0](T+3) | P8 ...      stg B[1][0](T+3) vm8
// Each phase: reads/stage -> barrier -> lgkmcnt(0)+sched_barrier -> setprio(1)
// 16 MFMA setprio(0) -> [vmcnt(8) even phases] -> barrier.
// EPI: 0 gelu rowmax; 1 gelu + f32 store + rowmax; 2 dequant store; 3 gelu+i8.
template <int EPI>
__global__ __launch_bounds__(512, 2) void gemm8_i8_k(const int8_t* __restrict__ A,
                                                     const int8_t* __restrict__ B, int K,
                                                     int NB_X,
                                                     float* __restrict__ Cf,
                                                     int8_t* __restrict__ Cq, int ldc,
                                                     const float* __restrict__ rowf,
                                                     const float* __restrict__ wscp,
                                                     unsigned* __restrict__ amax) {
  __shared__ __align__(16) int8_t L[131072];
  const int tid = threadIdx.x;
  const int wave = tid >> 6, lane = tid & 63;
  const int hi = lane >> 4, lo = lane & 15;
  const int wr = wave >> 2, wc = wave & 3;

  const int nwg = gridDim.x;  // multiple of 8 for both grids
  int bid = blockIdx.x;
  bid = (bid & 7) * (nwg >> 3) + (bid >> 3);
  const int bx = bid % NB_X, by = bid / NB_X;
  const int row0 = by * 256, col0 = bx * 256;

  const int srow = lane >> 2;
  const int skb = ((lane & 3) ^ ((lane >> 3) & 3)) * 16;
  const size_t aR0 = (size_t)(row0 + wave * 16 + srow) * K + skb;
  const size_t aR1 = (size_t)(row0 + (8 + wave) * 16 + srow) * K + skb;
  const size_t bR0 = (size_t)(col0 + wave * 16 + srow) * K + skb;
  const size_t bR1 = (size_t)(col0 + (8 + wave) * 16 + srow) * K + skb;
  const int NT = K >> 7;

  v4i acc[8][4];
#pragma unroll
  for (int m = 0; m < 8; ++m)
#pragma unroll
    for (int n = 0; n < 4; ++n) acc[m][n] = (v4i){0, 0, 0, 0};

  const int roff = lo * 64 + ((hi ^ ((lo >> 1) & 3)) * 16);

#define AREG(buf, h) (((buf) * 2 + (h)) * 16384)
#define BREG(buf, h) (65536 + ((buf) * 2 + (h)) * 16384)
#define STG_A(buf, h, TT)                                                      \
  do {                                                                         \
    const int tt_ = ((TT) < NT - 1) ? (TT) : (NT - 1);                         \
    const size_t ko_ = (size_t)tt_ * 128 + (size_t)(h) * 64;                   \
    gload16(A + aR0 + ko_, &L[AREG(buf, h) + wave * 1024]);                    \
    gload16(A + aR1 + ko_, &L[AREG(buf, h) + (8 + wave) * 1024]);              \
  } while (0)
#define STG_B(buf, h, TT)                                                      \
  do {                                                                         \
    const int tt_ = ((TT) < NT - 1) ? (TT) : (NT - 1);                         \
    const size_t ko_ = (size_t)tt_ * 128 + (size_t)(h) * 64;                   \
    gload16(B + bR0 + ko_, &L[BREG(buf, h) + wave * 1024]);                    \
    gload16(B + bR1 + ko_, &L[BREG(buf, h) + (8 + wave) * 1024]);              \
  } while (0)
#define DS_LO(buf, h)                                                          \
  af0 = *(const v4i*)&L[AREG(buf, h) + (wr * 8 + 0) * 1024 + roff];            \
  af1 = *(const v4i*)&L[AREG(buf, h) + (wr * 8 + 1) * 1024 + roff];            \
  af2 = *(const v4i*)&L[AREG(buf, h) + (wr * 8 + 2) * 1024 + roff];            \
  af3 = *(const v4i*)&L[AREG(buf, h) + (wr * 8 + 3) * 1024 + roff];            \
  bf0 = *(const v4i*)&L[BREG(buf, h) + (wc * 4 + 0) * 1024 + roff];            \
  bf1 = *(const v4i*)&L[BREG(buf, h) + (wc * 4 + 1) * 1024 + roff];            \
  bf2 = *(const v4i*)&L[BREG(buf, h) + (wc * 4 + 2) * 1024 + roff];            \
  bf3 = *(const v4i*)&L[BREG(buf, h) + (wc * 4 + 3) * 1024 + roff];
#define DS_HI(buf, h)                                                          \
  af0 = *(const v4i*)&L[AREG(buf, h) + (wr * 8 + 4) * 1024 + roff];            \
  af1 = *(const v4i*)&L[AREG(buf, h) + (wr * 8 + 5) * 1024 + roff];            \
  af2 = *(const v4i*)&L[AREG(buf, h) + (wr * 8 + 6) * 1024 + roff];            \
  af3 = *(const v4i*)&L[AREG(buf, h) + (wr * 8 + 7) * 1024 + roff];
#define MFMA16(mb)                                                             \
  __builtin_amdgcn_s_setprio(1);                                               \
  acc[mb + 0][0] = __builtin_amdgcn_mfma_i32_16x16x64_i8(af0, bf0, acc[mb + 0][0], 0, 0, 0); \
  acc[mb + 0][1] = __builtin_amdgcn_mfma_i32_16x16x64_i8(af0, bf1, acc[mb + 0][1], 0, 0, 0); \
  acc[mb + 0][2] = __builtin_amdgcn_mfma_i32_16x16x64_i8(af0, bf2, acc[mb + 0][2], 0, 0, 0); \
  acc[mb + 0][3] = __builtin_amdgcn_mfma_i32_16x16x64_i8(af0, bf3, acc[mb + 0][3], 0, 0, 0); \
  acc[mb + 1][0] = __builtin_amdgcn_mfma_i32_16x16x64_i8(af1, bf0, acc[mb + 1][0], 0, 0, 0); \
  acc[mb + 1][1] = __builtin_amdgcn_mfma_i32_16x16x64_i8(af1, bf1, acc[mb + 1][1], 0, 0, 0); \
  acc[mb + 1][2] = __builtin_amdgcn_mfma_i32_16x16x64_i8(af1, bf2, acc[mb + 1][2], 0, 0, 0); \
  acc[mb + 1][3] = __builtin_amdgcn_mfma_i32_16x16x64_i8(af1, bf3, acc[mb + 1][3], 0, 0, 0); \
  acc[mb + 2][0] = __builtin_amdgcn_mfma_i32_16x16x64_i8(af2, bf0, acc[mb + 2][0], 0, 0, 0); \
  acc[mb + 2][1] = __builtin_amdgcn_mfma_i32_16x16x64_i8(af2, bf1, acc[mb + 2][1], 0, 0, 0); \
  acc[mb + 2][2] = __builtin_amdgcn_mfma_i32_16x16x64_i8(af2, bf2, acc[mb + 2][2], 0, 0, 0); \
  acc[mb + 2][3] = __builtin_amdgcn_mfma_i32_16x16x64_i8(af2, bf3, acc[mb + 2][3], 0, 0, 0); \
  acc[mb + 3][0] = __builtin_amdgcn_mfma_i32_16x16x64_i8(af3, bf0, acc[mb + 3][0], 0, 0, 0); \
  acc[mb + 3][1] = __builtin_amdgcn_mfma_i32_16x16x64_i8(af3, bf1, acc[mb + 3][1], 0, 0, 0); \
  acc[mb + 3][2] = __builtin_amdgcn_mfma_i32_16x16x64_i8(af3, bf2, acc[mb + 3][2], 0, 0, 0); \
  acc[mb + 3][3] = __builtin_amdgcn_mfma_i32_16x16x64_i8(af3, bf3, acc[mb + 3][3], 0, 0, 0); \
  __builtin_amdgcn_s_setprio(0);
#define BAR1                                                                   \
  __builtin_amdgcn_s_barrier();                                                \
  asm volatile("s_waitcnt lgkmcnt(0)" ::: "memory");                           \
  __builtin_amdgcn_sched_barrier(0);
#define BAR2N __builtin_amdgcn_s_barrier();
#define BAR2V                                                                  \
  asm volatile("s_waitcnt vmcnt(8)" ::: "memory");                             \
  __builtin_amdgcn_s_barrier();

  // prologue: queue = [Ah0(0),Bh0(0),Ah1(0),Bh1(0),Ah0(1),Bh0(1)]
  STG_A(0, 0, 0);
  STG_B(0, 0, 0);
  STG_A(0, 1, 0);
  STG_B(0, 1, 0);
  STG_A(1, 0, 1);
  STG_B(1, 0, 1);
  asm volatile("s_waitcnt vmcnt(8)" ::: "memory");
  __builtin_amdgcn_s_barrier();

  const int NITER = NT >> 1;
#pragma unroll 1
  for (int it = 0; it < NITER; ++it) {
    const int T = it * 2;
    v4i af0, af1, af2, af3, bf0, bf1, bf2, bf3;
    DS_LO(0, 0); STG_A(1, 1, T + 1); BAR1; MFMA16(0); BAR2N;      // P1
    DS_HI(0, 0); STG_B(1, 1, T + 1); BAR1; MFMA16(4); BAR2V;      // P2
    DS_LO(0, 1); STG_A(0, 0, T + 2); BAR1; MFMA16(0); BAR2N;      // P3
    DS_HI(0, 1); STG_B(0, 0, T + 2); BAR1; MFMA16(4); BAR2V;      // P4
    DS_LO(1, 0); STG_A(0, 1, T + 2); BAR1; MFMA16(0); BAR2N;      // P5
    DS_HI(1, 0); STG_B(0, 1, T + 2); BAR1; MFMA16(4); BAR2V;      // P6
    DS_LO(1, 1); STG_A(1, 0, T + 3); BAR1; MFMA16(0); BAR2N;      // P7
    DS_HI(1, 1); STG_B(1, 0, T + 3); BAR1; MFMA16(4); BAR2V;      // P8
  }
  asm volatile("s_waitcnt vmcnt(0)" ::: "memory");

  // ---- epilogue ----
  const float mw = wscp[0];
#pragma unroll
  for (int m = 0; m < 8; ++m) {
#pragma unroll
    for (int r = 0; r < 4; ++r) {
      const int grow = row0 + wr * 128 + m * 16 + hi * 4 + r;
      const float f = rowf[grow] * mw;
      if constexpr (EPI == 0 || EPI == 1) {
        float rmax = 0.f;
#pragma unroll
        for (int n = 0; n < 4; ++n) {
          const int gcol = col0 + wc * 64 + n * 16 + lo;
          const float c = (float)acc[m][n][r] * f;
          const float gv = gelu_fast(c);
          if constexpr (EPI == 1) Cf[(size_t)grow * ldc + gcol] = gv;
          rmax = fmaxf(rmax, fabsf(gv));
        }
#pragma unroll
        for (int sh = 1; sh < 16; sh <<= 1) rmax = fmaxf(rmax, __shfl_xor(rmax, sh));
        if (lo == 0) atomicMax(&amax[grow], __float_as_uint(rmax));
      } else if constexpr (EPI == 3) {
        const double s = 127.0 / fmax((double)__uint_as_float(amax[grow]), 1e-5);
#pragma unroll
        for (int n = 0; n < 4; ++n) {
          const int gcol = col0 + wc * 64 + n * 16 + lo;
          const float c = (float)acc[m][n][r] * f;
          const float gv = gelu_fast(c);
          Cq[(size_t)grow * ldc + gcol] =
              (int8_t)clampi((int)__builtin_rint((double)gv * s), -128, 127);
        }
      } else {
#pragma unroll
        for (int n = 0; n < 4; ++n) {
          const int gcol = col0 + wc * 64 + n * 16 + lo;
          Cf[(size_t)grow * ldc + gcol] = (float)acc[m][n][r] * f;
        }
      }
    }
  }
}

__global__ void fill_k(float* p, int n, float v) {
  int i = blockIdx.x * 256 + threadIdx.x;
  if (i < n) p[i] = v;
}

extern "C" void kernel_launch(void* const* d_in, const int* in_sizes, int n_in, void* d_out,
                              int out_size, void* d_ws, size_t ws_size, hipStream_t stream) {
  const float* x = (const float*)d_in[0];
  const float* w1 = (const float*)d_in[1];
  const float* w2 = (const float*)d_in[2];
  const float* gamma = (const float*)d_in[3];
  float* out = (float*)d_out;
  char* ws = (char*)d_ws;

  const size_t SQX = (size_t)N_TOK * D_DIM;
  const size_t SQW1 = (size_t)D_HID * D_DIM;
  const size_t SQW2 = (size_t)D_DIM * D_HID;
  const size_t SQH = (size_t)N_TOK * D_HID;
  const size_t SG = (size_t)N_TOK * D_HID * 4;

  size_t off = 0;
  int8_t* qx = (int8_t*)(ws + off);  off += SQX;
  int8_t* qw1 = (int8_t*)(ws + off); off += SQW1;
  int8_t* qw2 = (int8_t*)(ws + off); off += SQW2;
  int8_t* qh = (int8_t*)(ws + off);  off += SQH;
  float* sxinv = (float*)(ws + off);       off += (size_t)N_TOK * 4;
  unsigned* amaxh = (unsigned*)(ws + off); off += (size_t)N_TOK * 4;
  float* shinv = (float*)(ws + off);       off += (size_t)N_TOK * 4;
  double* wpart = (double*)(ws + off);     off += 2048 * 8;
  double* swd = (double*)(ws + off);       off += 2 * 8;
  float* wsc = (float*)(ws + off);         off += 2 * 4;
  const size_t needB = off;
  float* g = (float*)(ws + off);
  const size_t needA = off + SG;

  if (ws_size < needB) {
    const float v = 100000.0f + (float)(ws_size >> 20);
    fill_k<<<(out_size + 255) / 256, 256, 0, stream>>>(out, out_size, v);
    return;
  }
  const bool pathA = (ws_size >= needA);

  hipMemsetAsync(amaxh, 0, (size_t)N_TOK * 4, stream);
  wsum_k<<<2048, 256, 0, stream>>>(w1, w2, wpart);
  wfinal_k<<<1, 256, 0, stream>>>(wpart, swd, wsc);
  wquant_k<<<16384, 256, 0, stream>>>(w1, qw1, swd, 0);
  wquant_k<<<16384, 256, 0, stream>>>(w2, qw2, swd, 1);
  rmsq_k<<<N_TOK, 256, 0, stream>>>(x, gamma, qx, sxinv);

  const int nwg1 = (N_TOK / 256) * (D_HID / 256);  // 1024
  const int nwg2 = (N_TOK / 256) * (D_DIM / 256);  // 256
  if (pathA) {
    gemm8_i8_k<1><<<nwg1, 512, 0, stream>>>(qx, qw1, D_DIM, D_HID / 256, g, nullptr,
                                            D_HID, sxinv, wsc + 0, amaxh);
    hquant_k<<<N_TOK, 256, 0, stream>>>(g, qh, amaxh, shinv);
  } else {
    gemm8_i8_k<0><<<nwg1, 512, 0, stream>>>(qx, qw1, D_DIM, D_HID / 256, nullptr, nullptr,
                                            D_HID, sxinv, wsc + 0, amaxh);
    scalefix_k<<<(N_TOK + 255) / 256, 256, 0, stream>>>(amaxh, shinv);
    gemm8_i8_k<3><<<nwg1, 512, 0, stream>>>(qx, qw1, D_DIM, D_HID / 256, nullptr, qh,
                                            D_HID, sxinv, wsc + 0, amaxh);
  }
  gemm8_i8_k<2><<<nwg2, 512, 0, stream>>>(qh, qw2, D_HID, D_DIM / 256, out, nullptr,
                                          D_DIM, shinv, wsc + 1, nullptr);
}